// Round 5
// baseline (370.392 us; speedup 1.0000x reference)
//
#include <hip/hip_runtime.h>

// Shapes (fixed per setup_inputs): n=1, C=256, t=8, h=64, w=64, heads=8, S=134
#define SS   134
#define HWP  4096     // h*w
#define THW  32768    // t*h*w

typedef float f32x4 __attribute__((ext_vector_type(4)));
typedef short bf16x8 __attribute__((ext_vector_type(8)));
typedef short bf16x4 __attribute__((ext_vector_type(4)));

__device__ __forceinline__ unsigned short f2bf(float f) {
  unsigned int u = __float_as_uint(f);
  u += 0x7fff + ((u >> 16) & 1);  // RNE (inputs are finite normals)
  return (unsigned short)(u >> 16);
}

// ---------------------------------------------------------------------------
// W -> bf16, once. Wbf lives in d_out (128 KB): attn_t fully overwrites O
// afterwards; stream order (w2bf -> conv -> attn_t) makes the aliasing safe.
// ---------------------------------------------------------------------------
__global__ __launch_bounds__(256) void w2bf(const float* __restrict__ W,
                                            unsigned short* __restrict__ Wbf) {
  const int i = (blockIdx.x * 256 + threadIdx.x) * 4;  // grid 64 -> 65536
  const float4 w4 = *(const float4*)&W[i];
  bf16x4 b;
  b.x = (short)f2bf(w4.x);
  b.y = (short)f2bf(w4.y);
  b.z = (short)f2bf(w4.z);
  b.w = (short)f2bf(w4.w);
  *(bf16x4*)&Wbf[i] = b;
}

// ---------------------------------------------------------------------------
// 1x1 conv as bf16-MFMA GEMM: PV[o][x] = sum_c W[o][c] * V[c][x] + bias[o]
// (unchanged)
// ---------------------------------------------------------------------------
__global__ __launch_bounds__(256) void conv1x1_v3(
    const float* __restrict__ V, const unsigned short* __restrict__ Wbf,
    const float* __restrict__ bias, float* __restrict__ PV) {
  __shared__ unsigned short sW[256 * 40];  // [o][c-k0], bf16, row stride 40
  __shared__ unsigned short sV[32 * 40];   // [x][c-k0], bf16 (transposed)
  const int tid = threadIdx.x;
  const int x0 = blockIdx.x * 32;
  const int lane = tid & 63;
  const int wv = tid >> 6;   // wave 0..3
  const int m = lane & 15;   // MFMA free-dim index
  const int q = lane >> 4;   // MFMA quad 0..3

  f32x4 acc[4][2];
#pragma unroll
  for (int i = 0; i < 4; ++i)
#pragma unroll
    for (int j = 0; j < 2; ++j)
      acc[i][j] = (f32x4){0.f, 0.f, 0.f, 0.f};

  for (int k0 = 0; k0 < 256; k0 += 32) {
    // stage W slice [256 o][32 c] bf16: 1024 short8 copies
#pragma unroll
    for (int r = 0; r < 4; ++r) {
      const int s8 = r * 256 + tid;   // short8 slot 0..1023
      const int o = s8 >> 2;
      const int c8 = (s8 & 3) * 8;
      *(bf16x8*)&sW[o * 40 + c8] = *(const bf16x8*)&Wbf[o * 256 + k0 + c8];
    }
    {
      const int c = tid >> 3;          // 0..31
      const int x4 = (tid & 7) * 4;    // 0..28
      const float4 v4 = *(const float4*)&V[(size_t)(k0 + c) * THW + x0 + x4];
      sV[(x4 + 0) * 40 + c] = f2bf(v4.x);
      sV[(x4 + 1) * 40 + c] = f2bf(v4.y);
      sV[(x4 + 2) * 40 + c] = f2bf(v4.z);
      sV[(x4 + 3) * 40 + c] = f2bf(v4.w);
    }
    __syncthreads();
    bf16x8 fa[4], fb[2];
#pragma unroll
    for (int i = 0; i < 4; ++i)
      fa[i] = *(const bf16x8*)&sW[(wv * 64 + i * 16 + m) * 40 + q * 8];
#pragma unroll
    for (int j = 0; j < 2; ++j)
      fb[j] = *(const bf16x8*)&sV[(j * 16 + m) * 40 + q * 8];
#pragma unroll
    for (int i = 0; i < 4; ++i)
#pragma unroll
      for (int j = 0; j < 2; ++j)
        acc[i][j] = __builtin_amdgcn_mfma_f32_16x16x32_bf16(fa[i], fb[j], acc[i][j], 0, 0, 0);
    __syncthreads();
  }

#pragma unroll
  for (int i = 0; i < 4; ++i) {
#pragma unroll
    for (int r = 0; r < 4; ++r) {
      const int o = wv * 64 + i * 16 + q * 4 + r;
      const float b = bias[o];
#pragma unroll
      for (int j = 0; j < 2; ++j)
        PV[(size_t)o * THW + x0 + j * 16 + m] = acc[i][j][r] + b;
    }
  }
}

// ---------------------------------------------------------------------------
// t axis, standalone streaming kernel: O[c][tq][hw] = sum_s A_t[s][tq][hw] *
// pv[c][s][hw].  Every pv element is read by exactly ONE block (was re-read
// x8 over tq inside the old attn_th = 256MB of L2-miss traffic, the dominant
// contributor to the ~1GB/dispatch that pegged the L2-fill path).
//   Block = (hd, cb of 8 c, hw-tile of 256), grid 512, 256 thr, no LDS.
//   Thread: xi = (tid&63)*4 (f32x4, wave covers 1KB contiguous),
//           cq = tid>>6, c = cb*8 + cq*2 + ci (ci 0..1).
//   acc[8 tq][2 ci] f32x4 (64 VGPRs), s ascending -> same accumulation
//   order as before (bitwise identical).
// ---------------------------------------------------------------------------
__global__ __launch_bounds__(256) void attn_t(
    const float* __restrict__ A, const float* __restrict__ PV,
    float* __restrict__ O) {
  const int b = blockIdx.x;  // hd + 8*(cb + 4*xt), grid 512
  const int hd = b & 7;
  const int cb = (b >> 3) & 3;
  const int xt = b >> 5;  // 0..15
  const int tid = threadIdx.x;
  const int xi = xt * 256 + (tid & 63) * 4;  // hw float offset
  const int cq = tid >> 6;                   // 0..3

  const float* __restrict__ At = A + (size_t)hd * SS * THW + xi;
  const size_t pvh = (size_t)hd * 32 * THW;

  f32x4 acc[8][2];
#pragma unroll
  for (int t = 0; t < 8; ++t)
#pragma unroll
    for (int ci = 0; ci < 2; ++ci)
      acc[t][ci] = (f32x4){0.f, 0.f, 0.f, 0.f};

  for (int s = 0; s < 8; ++s) {
    f32x4 pvv[2];
#pragma unroll
    for (int ci = 0; ci < 2; ++ci) {
      const int c = cb * 8 + cq * 2 + ci;
      pvv[ci] = *(const f32x4*)&PV[pvh + (size_t)c * THW + (size_t)s * HWP + xi];
    }
#pragma unroll
    for (int t = 0; t < 8; ++t) {
      const f32x4 a = *(const f32x4*)&At[(size_t)s * THW + (size_t)t * HWP];
#pragma unroll
      for (int ci = 0; ci < 2; ++ci)
        acc[t][ci] += a * pvv[ci];
    }
  }

#pragma unroll
  for (int t = 0; t < 8; ++t)
#pragma unroll
    for (int ci = 0; ci < 2; ++ci) {
      const int c = cb * 8 + cq * 2 + ci;
      *(f32x4*)&O[pvh + (size_t)c * THW + (size_t)t * HWP + xi] = acc[t][ci];
    }
}

// ---------------------------------------------------------------------------
// h axis, RMW on O (adds to the t-part). R2's proven coalesced structure,
// t-axis removed, full c=32 per block (no chb split -> A_h read once, 64MB
// total, was 131MB). acc initialized FROM O so the accumulation order stays
// t-then-h (bitwise identical; fp32 store/load is lossless).
//   Block = (hd, tq, qb of 16 q), grid 256, 512 thr, 128KB LDS (1 blk/CU).
//   lane: w4 = (lane&15)*4 (full w, f32x4), cl = lane>>4 (4 c)
//   wave wv 0..7: ch = wv&1 (c half), qg = wv>>1; q = qb*16+qg*4+qi (qi 0..3)
//   c = ch*16 + g*4 + cl (g 0..3).  acc[4 qi][4 g] f32x4 over w.
// pv chunk double-buffered in LDS ([2][8 pp][32 c][64 w] = 128 KB);
// global->reg prefetch issued before compute so staging hides under FMA.
// NOTE: plain __launch_bounds__ — the min-waves arg capped VGPRs at 64 and
// spilled in R3/R4 (WRITE_SIZE +20..30MB).
// ---------------------------------------------------------------------------
__global__ __launch_bounds__(512) void attn_h(
    const float* __restrict__ A, const float* __restrict__ PV,
    float* __restrict__ O) {
  const int b = blockIdx.x;  // hd + 8*(qb + 4*tq), grid 256
  const int hd = b & 7;
  const int qb = (b >> 3) & 3;
  const int tq = b >> 5;  // 0..7
  const int tid = threadIdx.x;
  const int lane = tid & 63;
  const int wv = tid >> 6;         // 0..7
  const int w4 = (lane & 15) * 4;  // w float-offset (f32x4)
  const int cl = lane >> 4;        // 0..3
  const int ch = wv & 1;           // c half
  const int qg = wv >> 1;          // 0..3
  const int q0 = qb * 16 + qg * 4;

  __shared__ float slab[2][8 * 32 * 64];  // [buf][pp][c][w] = 128 KB

  const float* __restrict__ Ab = A + (size_t)hd * SS * THW + (size_t)tq * HWP;
  const size_t pvh = (size_t)hd * 32 * THW;
  const float* __restrict__ PVh = PV + pvh;

  // init acc from O (t-part, RMW); issued first so latency hides under staging
  f32x4 acc[4][4];  // [qi][g]
#pragma unroll
  for (int qi = 0; qi < 4; ++qi) {
    const int q = q0 + qi;
#pragma unroll
    for (int g = 0; g < 4; ++g) {
      const int c = ch * 16 + g * 4 + cl;
      acc[qi][g] =
          *(const f32x4*)&O[pvh + (size_t)c * THW + (size_t)tq * HWP + q * 64 + w4];
    }
  }

  // staging map: thread covers pp = 0..7 at fixed (c_s, w4s)
  const int c_s = tid >> 4;          // 0..31
  const int w4s = (tid & 15) * 4;
  const float* __restrict__ pvstage =
      PVh + (size_t)c_s * THW + (size_t)tq * HWP + w4s;
  const int sbase = c_s * 64 + w4s;  // float offset within a pp plane (32c*64w)

  // chunk-0 prefetch (p = 0..7)
  f32x4 stg[8];
#pragma unroll
  for (int r = 0; r < 8; ++r) stg[r] = *(const f32x4*)&pvstage[r * 64];
#pragma unroll
  for (int r = 0; r < 8; ++r)
    *(f32x4*)&slab[0][r * 2048 + sbase] = stg[r];
  __syncthreads();

  // ---- h axis: 8 chunks of 8 p, double-buffered ----
  for (int ck = 0; ck < 8; ++ck) {
    const int cur = ck & 1;
    if (ck < 7) {
      // issue next chunk's global loads now; they complete under the FMAs
#pragma unroll
      for (int r = 0; r < 8; ++r)
        stg[r] = *(const f32x4*)&pvstage[((ck + 1) * 8 + r) * 64];
    }
#pragma unroll
    for (int pp = 0; pp < 8; ++pp) {
      const int p = ck * 8 + pp;
      f32x4 a[4];
#pragma unroll
      for (int qi = 0; qi < 4; ++qi) {
        const int q = q0 + qi;
        const int row = p - (q < p ? 1 : 0);  // 0..63 (p==q load masked)
        f32x4 av = *(const f32x4*)&Ab[(size_t)(8 + row) * THW + q * 64 + w4];
        if (q == p) av = (f32x4){0.f, 0.f, 0.f, 0.f};
        a[qi] = av;
      }
      f32x4 v[4];
#pragma unroll
      for (int g = 0; g < 4; ++g)
        v[g] = *(const f32x4*)&slab[cur][pp * 2048 + (g * 4 + cl + ch * 16) * 64 + w4];
#pragma unroll
      for (int qi = 0; qi < 4; ++qi)
#pragma unroll
        for (int g = 0; g < 4; ++g)
          acc[qi][g] += a[qi] * v[g];
    }
    __syncthreads();
    if (ck < 7) {
#pragma unroll
      for (int r = 0; r < 8; ++r)
        *(f32x4*)&slab[cur ^ 1][r * 2048 + sbase] = stg[r];
      __syncthreads();
    }
  }

  // ---- store (t + h partial) ----
#pragma unroll
  for (int qi = 0; qi < 4; ++qi) {
    const int q = q0 + qi;
#pragma unroll
    for (int g = 0; g < 4; ++g) {
      const int c = ch * 16 + g * 4 + cl;
      *(f32x4*)&O[pvh + (size_t)c * THW + (size_t)tq * HWP + q * 64 + w4] =
          acc[qi][g];
    }
  }
}

// ---------------------------------------------------------------------------
// w axis, read-modify-write on O. (unchanged)
// ---------------------------------------------------------------------------
__global__ __launch_bounds__(256) void attn_w(
    const float* __restrict__ A, const float* __restrict__ PV,
    float* __restrict__ O) {
  const int b = blockIdx.x;  // hb + 16*tq + 128*hd, grid 1024
  const int hb = b & 15;
  const int tq = (b >> 4) & 7;
  const int hd = b >> 7;
  const int tid = threadIdx.x;
  const int wq = tid & 63;
  const int cg = tid >> 6;  // 0..3
  const int h0 = hb * 4;

  __shared__ float slab[32 * 64 * 4];  // [c][pw][h4]

  const float* __restrict__ Ab = A + (size_t)hd * SS * THW + (size_t)tq * HWP;
  const size_t pvh = (size_t)hd * 32 * THW;

  // stage pv w-slab (transpose w<->h minor dims)
#pragma unroll 4
  for (int i = 0; i < 8; ++i) {
    const int fid = tid + i * 256;     // 0..2047
    const int w4s = (fid & 15) * 4;    // 0..60
    const int h = (fid >> 4) & 3;      // 0..3
    const int c = fid >> 6;            // 0..31
    const f32x4 v =
        *(const f32x4*)&PV[pvh + (size_t)c * THW + (size_t)tq * HWP + (h0 + h) * 64 + w4s];
    slab[(c * 64 + w4s + 0) * 4 + h] = v.x;
    slab[(c * 64 + w4s + 1) * 4 + h] = v.y;
    slab[(c * 64 + w4s + 2) * 4 + h] = v.z;
    slab[(c * 64 + w4s + 3) * 4 + h] = v.w;
  }

  // prefetch current O tile (RMW) while staging completes
  f32x4 racc[8];
#pragma unroll
  for (int ci = 0; ci < 8; ++ci) {
    const int c = cg + ci * 4;
    f32x4 r;
#pragma unroll
    for (int hh = 0; hh < 4; ++hh)
      r[hh] = O[pvh + (size_t)c * THW + (size_t)tq * HWP + (h0 + hh) * 64 + wq];
    racc[ci] = r;
  }
  __syncthreads();

#pragma unroll 2
  for (int p = 0; p < 64; ++p) {
    const int row = 71 + p - (wq <= p ? 1 : 0);  // 70..133, in-bounds always
    const float* pa = Ab + (size_t)row * THW + h0 * 64 + wq;
    f32x4 a;
    a.x = pa[0];
    a.y = pa[64];
    a.z = pa[128];
    a.w = pa[192];
    if (p == wq) a = (f32x4){0.f, 0.f, 0.f, 0.f};
#pragma unroll
    for (int ci = 0; ci < 8; ++ci) {
      const f32x4 v = *(const f32x4*)&slab[(cg + ci * 4) * 256 + p * 4];
      racc[ci] += a * v;
    }
  }

  // ---- store (RMW result) ----
#pragma unroll
  for (int ci = 0; ci < 8; ++ci) {
    const int c = cg + ci * 4;
#pragma unroll
    for (int hh = 0; hh < 4; ++hh)
      O[pvh + (size_t)c * THW + (size_t)tq * HWP + (h0 + hh) * 64 + wq] = racc[ci][hh];
  }
}

extern "C" void kernel_launch(void* const* d_in, const int* in_sizes, int n_in,
                              void* d_out, int out_size, void* d_ws, size_t ws_size,
                              hipStream_t stream) {
  const float* A = (const float*)d_in[0];     // [8*134][8][64][64]
  const float* V = (const float*)d_in[1];     // [256][8][64][64]
  const float* W = (const float*)d_in[2];     // [256][256] (o, c)
  const float* bias = (const float*)d_in[3];  // [256]
  float* out = (float*)d_out;                 // [256][8][64][64]
  float* pv = (float*)d_ws;                   // 32 MB scratch: pv[o][t][h][w]

  unsigned short* Wbf = (unsigned short*)d_out;  // temp 128 KB, dead after conv

  w2bf<<<dim3(64), 256, 0, stream>>>(W, Wbf);
  conv1x1_v3<<<dim3(1024), 256, 0, stream>>>(V, Wbf, bias, pv);
  attn_t<<<dim3(512), 256, 0, stream>>>(A, pv, out);
  attn_h<<<dim3(256), 512, 0, stream>>>(A, pv, out);
  attn_w<<<dim3(1024), 256, 0, stream>>>(A, pv, out);
}

// Round 6
// 353.312 us; speedup vs baseline: 1.0483x; 1.0483x over previous
//
#include <hip/hip_runtime.h>

// Shapes (fixed per setup_inputs): n=1, C=256, t=8, h=64, w=64, heads=8, S=134
#define SS   134
#define HWP  4096     // h*w
#define THW  32768    // t*h*w

typedef float f32x4 __attribute__((ext_vector_type(4)));
typedef short bf16x8 __attribute__((ext_vector_type(8)));
typedef short bf16x4 __attribute__((ext_vector_type(4)));

__device__ __forceinline__ unsigned short f2bf(float f) {
  unsigned int u = __float_as_uint(f);
  u += 0x7fff + ((u >> 16) & 1);  // RNE (inputs are finite normals)
  return (unsigned short)(u >> 16);
}

// ---------------------------------------------------------------------------
// W -> bf16, once. Wbf lives in d_out (128 KB): attn_t fully overwrites O
// afterwards; stream order (w2bf -> conv -> attn_t) makes the aliasing safe.
// ---------------------------------------------------------------------------
__global__ __launch_bounds__(256) void w2bf(const float* __restrict__ W,
                                            unsigned short* __restrict__ Wbf) {
  const int i = (blockIdx.x * 256 + threadIdx.x) * 4;  // grid 64 -> 65536
  const float4 w4 = *(const float4*)&W[i];
  bf16x4 b;
  b.x = (short)f2bf(w4.x);
  b.y = (short)f2bf(w4.y);
  b.z = (short)f2bf(w4.z);
  b.w = (short)f2bf(w4.w);
  *(bf16x4*)&Wbf[i] = b;
}

// ---------------------------------------------------------------------------
// 1x1 conv v4: PV[o][x] = sum_c W[o][c]*V[c][x] + bias[o], bf16 MFMA.
// Old version re-staged ALL of W per block (1024 blocks x 128KB = 128MB of
// pure staging for a 4.3-GFLOP GEMM). v4: x-tile 128 (grid 256), 512 thr,
// W staged ONCE per block into sW[256][260] (130KB LDS), V double-buffered
// (sV[2][128][40] bf16). k0 ascending, same 16x16x32 MFMA chain, same
// fragment/output mapping as the verified conv -> bitwise-identical PV.
//   wave wv 0..7: o-tiles i in {0,1}: o = wv*32 + i*16 + (q*4+r), all 8
//   x-tiles j: x = x0 + j*16 + m.  acc[2][8] f32x4.
// Single sync per k-step: write sV[cur^1] is safe (last read 2 steps ago,
// separated by a sync); readers of cur^1 wait for this step's sync.
// ---------------------------------------------------------------------------
__global__ __launch_bounds__(512) void conv1x1_v4(
    const float* __restrict__ V, const unsigned short* __restrict__ Wbf,
    const float* __restrict__ bias, float* __restrict__ PV) {
  __shared__ unsigned short sW[256 * 260];   // 130 KB, row stride 260
  __shared__ unsigned short sV[2][128 * 40]; // [buf][x][c], 2 x 10 KB
  const int tid = threadIdx.x;
  const int x0 = blockIdx.x * 128;  // grid 256
  const int lane = tid & 63;
  const int wv = tid >> 6;   // 0..7
  const int m = lane & 15;   // MFMA free-dim index
  const int q = lane >> 4;   // MFMA quad 0..3

  // ---- stage W once: thread copies o = tid>>1, half = (tid&1)*128 ----
  {
    const int o = tid >> 1;
    const int half = (tid & 1) * 128;
#pragma unroll
    for (int r = 0; r < 16; ++r)
      *(bf16x8*)&sW[o * 260 + half + r * 8] =
          *(const bf16x8*)&Wbf[o * 256 + half + r * 8];
  }

  // ---- V staging map: c_s = tid>>4 (0..31), x8 = (tid&15)*8 ----
  const int c_s = tid >> 4;
  const int x8 = (tid & 15) * 8;
  const float* __restrict__ vstage = V + (size_t)c_s * THW + x0 + x8;

  // stage k-step 0 into sV[0]
  {
    const float4 va = *(const float4*)&vstage[0];
    const float4 vb = *(const float4*)&vstage[4];
    sV[0][(x8 + 0) * 40 + c_s] = f2bf(va.x);
    sV[0][(x8 + 1) * 40 + c_s] = f2bf(va.y);
    sV[0][(x8 + 2) * 40 + c_s] = f2bf(va.z);
    sV[0][(x8 + 3) * 40 + c_s] = f2bf(va.w);
    sV[0][(x8 + 4) * 40 + c_s] = f2bf(vb.x);
    sV[0][(x8 + 5) * 40 + c_s] = f2bf(vb.y);
    sV[0][(x8 + 6) * 40 + c_s] = f2bf(vb.z);
    sV[0][(x8 + 7) * 40 + c_s] = f2bf(vb.w);
  }
  __syncthreads();

  f32x4 acc[2][8];
#pragma unroll
  for (int i = 0; i < 2; ++i)
#pragma unroll
    for (int j = 0; j < 8; ++j)
      acc[i][j] = (f32x4){0.f, 0.f, 0.f, 0.f};

  for (int kk = 0; kk < 8; ++kk) {
    const int cur = kk & 1;
    float4 pva, pvb;
    if (kk < 7) {  // prefetch next V chunk; completes under the MFMAs
      pva = *(const float4*)&vstage[(size_t)(kk + 1) * 32 * THW];
      pvb = *(const float4*)&vstage[(size_t)(kk + 1) * 32 * THW + 4];
    }
    bf16x8 fa[2], fb[8];
#pragma unroll
    for (int i = 0; i < 2; ++i)
      fa[i] = *(const bf16x8*)&sW[(wv * 32 + i * 16 + m) * 260 + kk * 32 + q * 8];
#pragma unroll
    for (int j = 0; j < 8; ++j)
      fb[j] = *(const bf16x8*)&sV[cur][(j * 16 + m) * 40 + q * 8];
#pragma unroll
    for (int i = 0; i < 2; ++i)
#pragma unroll
      for (int j = 0; j < 8; ++j)
        acc[i][j] = __builtin_amdgcn_mfma_f32_16x16x32_bf16(fa[i], fb[j], acc[i][j], 0, 0, 0);
    if (kk < 7) {
      const int nb = cur ^ 1;
      sV[nb][(x8 + 0) * 40 + c_s] = f2bf(pva.x);
      sV[nb][(x8 + 1) * 40 + c_s] = f2bf(pva.y);
      sV[nb][(x8 + 2) * 40 + c_s] = f2bf(pva.z);
      sV[nb][(x8 + 3) * 40 + c_s] = f2bf(pva.w);
      sV[nb][(x8 + 4) * 40 + c_s] = f2bf(pvb.x);
      sV[nb][(x8 + 5) * 40 + c_s] = f2bf(pvb.y);
      sV[nb][(x8 + 6) * 40 + c_s] = f2bf(pvb.z);
      sV[nb][(x8 + 7) * 40 + c_s] = f2bf(pvb.w);
    }
    __syncthreads();
  }

  // ---- epilogue ----
#pragma unroll
  for (int i = 0; i < 2; ++i) {
#pragma unroll
    for (int r = 0; r < 4; ++r) {
      const int o = wv * 32 + i * 16 + q * 4 + r;
      const float bo = bias[o];
#pragma unroll
      for (int j = 0; j < 8; ++j)
        PV[(size_t)o * THW + x0 + j * 16 + m] = acc[i][j][r] + bo;
    }
  }
}

// ---------------------------------------------------------------------------
// t axis, standalone streaming kernel (unchanged from R5).
// ---------------------------------------------------------------------------
__global__ __launch_bounds__(256) void attn_t(
    const float* __restrict__ A, const float* __restrict__ PV,
    float* __restrict__ O) {
  const int b = blockIdx.x;  // hd + 8*(cb + 4*xt), grid 512
  const int hd = b & 7;
  const int cb = (b >> 3) & 3;
  const int xt = b >> 5;  // 0..15
  const int tid = threadIdx.x;
  const int xi = xt * 256 + (tid & 63) * 4;  // hw float offset
  const int cq = tid >> 6;                   // 0..3

  const float* __restrict__ At = A + (size_t)hd * SS * THW + xi;
  const size_t pvh = (size_t)hd * 32 * THW;

  f32x4 acc[8][2];
#pragma unroll
  for (int t = 0; t < 8; ++t)
#pragma unroll
    for (int ci = 0; ci < 2; ++ci)
      acc[t][ci] = (f32x4){0.f, 0.f, 0.f, 0.f};

  for (int s = 0; s < 8; ++s) {
    f32x4 pvv[2];
#pragma unroll
    for (int ci = 0; ci < 2; ++ci) {
      const int c = cb * 8 + cq * 2 + ci;
      pvv[ci] = *(const f32x4*)&PV[pvh + (size_t)c * THW + (size_t)s * HWP + xi];
    }
#pragma unroll
    for (int t = 0; t < 8; ++t) {
      const f32x4 a = *(const f32x4*)&At[(size_t)s * THW + (size_t)t * HWP];
#pragma unroll
      for (int ci = 0; ci < 2; ++ci)
        acc[t][ci] += a * pvv[ci];
    }
  }

#pragma unroll
  for (int t = 0; t < 8; ++t)
#pragma unroll
    for (int ci = 0; ci < 2; ++ci) {
      const int c = cb * 8 + cq * 2 + ci;
      *(f32x4*)&O[pvh + (size_t)c * THW + (size_t)t * HWP + xi] = acc[t][ci];
    }
}

// ---------------------------------------------------------------------------
// h axis v6, RMW on O. Same coalesced structure as R5 but LDS halved to
// 64 KB (chunks of 4 p, double-buffered) -> 2 blocks/CU = 16 waves/CU
// (4/SIMD) at VGPR<=128 (plain launch_bounds; the min-waves arg forced
// VGPR=64 + spill in R3/R4 and poisoned both occupancy experiments).
// R5 evidence: latency-bound, retire ~1 VMEM/82cyc/CU at 6 live waves;
// doubling clean waves should ~halve duration. Single sync per chunk:
// writing cur^1 is safe (its readers finished before the previous sync).
// Accumulation order unchanged (p ascending) -> bitwise identical.
// ---------------------------------------------------------------------------
__global__ __launch_bounds__(512) void attn_h(
    const float* __restrict__ A, const float* __restrict__ PV,
    float* __restrict__ O) {
  const int b = blockIdx.x;  // hd + 8*(qb + 4*tq), grid 256
  const int hd = b & 7;
  const int qb = (b >> 3) & 3;
  const int tq = b >> 5;  // 0..7
  const int tid = threadIdx.x;
  const int lane = tid & 63;
  const int wv = tid >> 6;         // 0..7
  const int w4 = (lane & 15) * 4;  // w float-offset (f32x4)
  const int cl = lane >> 4;        // 0..3
  const int ch = wv & 1;           // c half
  const int qg = wv >> 1;          // 0..3
  const int q0 = qb * 16 + qg * 4;

  __shared__ float slab[2][4 * 32 * 64];  // [buf][pp][c][w] = 64 KB

  const float* __restrict__ Ab = A + (size_t)hd * SS * THW + (size_t)tq * HWP;
  const size_t pvh = (size_t)hd * 32 * THW;
  const float* __restrict__ PVh = PV + pvh;

  // init acc from O (t-part, RMW); issued first so latency hides under staging
  f32x4 acc[4][4];  // [qi][g]
#pragma unroll
  for (int qi = 0; qi < 4; ++qi) {
    const int q = q0 + qi;
#pragma unroll
    for (int g = 0; g < 4; ++g) {
      const int c = ch * 16 + g * 4 + cl;
      acc[qi][g] =
          *(const f32x4*)&O[pvh + (size_t)c * THW + (size_t)tq * HWP + q * 64 + w4];
    }
  }

  // staging map: thread covers pp = 0..3 at fixed (c_s, w4s)
  const int c_s = tid >> 4;          // 0..31
  const int w4s = (tid & 15) * 4;
  const float* __restrict__ pvstage =
      PVh + (size_t)c_s * THW + (size_t)tq * HWP + w4s;
  const int sbase = c_s * 64 + w4s;  // float offset within a pp plane (32c*64w)

  // chunk-0 prefetch (p = 0..3)
  f32x4 stg[4];
#pragma unroll
  for (int r = 0; r < 4; ++r) stg[r] = *(const f32x4*)&pvstage[r * 64];
#pragma unroll
  for (int r = 0; r < 4; ++r)
    *(f32x4*)&slab[0][r * 2048 + sbase] = stg[r];
  __syncthreads();

  // ---- h axis: 16 chunks of 4 p, double-buffered, 1 sync/chunk ----
  for (int ck = 0; ck < 16; ++ck) {
    const int cur = ck & 1;
    if (ck < 15) {
      // issue next chunk's global loads now; they complete under the FMAs
#pragma unroll
      for (int r = 0; r < 4; ++r)
        stg[r] = *(const f32x4*)&pvstage[((ck + 1) * 4 + r) * 64];
    }
#pragma unroll
    for (int pp = 0; pp < 4; ++pp) {
      const int p = ck * 4 + pp;
      f32x4 a[4];
#pragma unroll
      for (int qi = 0; qi < 4; ++qi) {
        const int q = q0 + qi;
        const int row = p - (q < p ? 1 : 0);  // 0..63 (p==q load masked)
        f32x4 av = *(const f32x4*)&Ab[(size_t)(8 + row) * THW + q * 64 + w4];
        if (q == p) av = (f32x4){0.f, 0.f, 0.f, 0.f};
        a[qi] = av;
      }
      f32x4 v[4];
#pragma unroll
      for (int g = 0; g < 4; ++g)
        v[g] = *(const f32x4*)&slab[cur][pp * 2048 + (g * 4 + cl + ch * 16) * 64 + w4];
#pragma unroll
      for (int qi = 0; qi < 4; ++qi)
#pragma unroll
        for (int g = 0; g < 4; ++g)
          acc[qi][g] += a[qi] * v[g];
    }
    if (ck < 15) {
#pragma unroll
      for (int r = 0; r < 4; ++r)
        *(f32x4*)&slab[cur ^ 1][r * 2048 + sbase] = stg[r];
    }
    __syncthreads();
  }

  // ---- store (t + h partial) ----
#pragma unroll
  for (int qi = 0; qi < 4; ++qi) {
    const int q = q0 + qi;
#pragma unroll
    for (int g = 0; g < 4; ++g) {
      const int c = ch * 16 + g * 4 + cl;
      *(f32x4*)&O[pvh + (size_t)c * THW + (size_t)tq * HWP + q * 64 + w4] =
          acc[qi][g];
    }
  }
}

// ---------------------------------------------------------------------------
// w axis, read-modify-write on O. Unchanged except p-loop unroll 2->4 for
// more loads in flight (latency-bound family).
// ---------------------------------------------------------------------------
__global__ __launch_bounds__(256) void attn_w(
    const float* __restrict__ A, const float* __restrict__ PV,
    float* __restrict__ O) {
  const int b = blockIdx.x;  // hb + 16*tq + 128*hd, grid 1024
  const int hb = b & 15;
  const int tq = (b >> 4) & 7;
  const int hd = b >> 7;
  const int tid = threadIdx.x;
  const int wq = tid & 63;
  const int cg = tid >> 6;  // 0..3
  const int h0 = hb * 4;

  __shared__ float slab[32 * 64 * 4];  // [c][pw][h4]

  const float* __restrict__ Ab = A + (size_t)hd * SS * THW + (size_t)tq * HWP;
  const size_t pvh = (size_t)hd * 32 * THW;

  // stage pv w-slab (transpose w<->h minor dims)
#pragma unroll 4
  for (int i = 0; i < 8; ++i) {
    const int fid = tid + i * 256;     // 0..2047
    const int w4s = (fid & 15) * 4;    // 0..60
    const int h = (fid >> 4) & 3;      // 0..3
    const int c = fid >> 6;            // 0..31
    const f32x4 v =
        *(const f32x4*)&PV[pvh + (size_t)c * THW + (size_t)tq * HWP + (h0 + h) * 64 + w4s];
    slab[(c * 64 + w4s + 0) * 4 + h] = v.x;
    slab[(c * 64 + w4s + 1) * 4 + h] = v.y;
    slab[(c * 64 + w4s + 2) * 4 + h] = v.z;
    slab[(c * 64 + w4s + 3) * 4 + h] = v.w;
  }

  // prefetch current O tile (RMW) while staging completes
  f32x4 racc[8];
#pragma unroll
  for (int ci = 0; ci < 8; ++ci) {
    const int c = cg + ci * 4;
    f32x4 r;
#pragma unroll
    for (int hh = 0; hh < 4; ++hh)
      r[hh] = O[pvh + (size_t)c * THW + (size_t)tq * HWP + (h0 + hh) * 64 + wq];
    racc[ci] = r;
  }
  __syncthreads();

#pragma unroll 4
  for (int p = 0; p < 64; ++p) {
    const int row = 71 + p - (wq <= p ? 1 : 0);  // 70..133, in-bounds always
    const float* pa = Ab + (size_t)row * THW + h0 * 64 + wq;
    f32x4 a;
    a.x = pa[0];
    a.y = pa[64];
    a.z = pa[128];
    a.w = pa[192];
    if (p == wq) a = (f32x4){0.f, 0.f, 0.f, 0.f};
#pragma unroll
    for (int ci = 0; ci < 8; ++ci) {
      const f32x4 v = *(const f32x4*)&slab[(cg + ci * 4) * 256 + p * 4];
      racc[ci] += a * v;
    }
  }

  // ---- store (RMW result) ----
#pragma unroll
  for (int ci = 0; ci < 8; ++ci) {
    const int c = cg + ci * 4;
#pragma unroll
    for (int hh = 0; hh < 4; ++hh)
      O[pvh + (size_t)c * THW + (size_t)tq * HWP + (h0 + hh) * 64 + wq] = racc[ci][hh];
  }
}

extern "C" void kernel_launch(void* const* d_in, const int* in_sizes, int n_in,
                              void* d_out, int out_size, void* d_ws, size_t ws_size,
                              hipStream_t stream) {
  const float* A = (const float*)d_in[0];     // [8*134][8][64][64]
  const float* V = (const float*)d_in[1];     // [256][8][64][64]
  const float* W = (const float*)d_in[2];     // [256][256] (o, c)
  const float* bias = (const float*)d_in[3];  // [256]
  float* out = (float*)d_out;                 // [256][8][64][64]
  float* pv = (float*)d_ws;                   // 32 MB scratch: pv[o][t][h][w]

  unsigned short* Wbf = (unsigned short*)d_out;  // temp 128 KB, dead after conv

  w2bf<<<dim3(64), 256, 0, stream>>>(W, Wbf);
  conv1x1_v4<<<dim3(256), 512, 0, stream>>>(V, Wbf, bias, pv);
  attn_t<<<dim3(512), 256, 0, stream>>>(A, pv, out);
  attn_h<<<dim3(256), 512, 0, stream>>>(A, pv, out);
  attn_w<<<dim3(1024), 256, 0, stream>>>(A, pv, out);
}

// Round 7
// 326.901 us; speedup vs baseline: 1.1330x; 1.0808x over previous
//
#include <hip/hip_runtime.h>

// Shapes (fixed per setup_inputs): n=1, C=256, t=8, h=64, w=64, heads=8, S=134
#define SS   134
#define HWP  4096     // h*w
#define THW  32768    // t*h*w

typedef float f32x4 __attribute__((ext_vector_type(4)));
typedef short bf16x8 __attribute__((ext_vector_type(8)));
typedef short bf16x4 __attribute__((ext_vector_type(4)));

__device__ __forceinline__ unsigned short f2bf(float f) {
  unsigned int u = __float_as_uint(f);
  u += 0x7fff + ((u >> 16) & 1);  // RNE (inputs are finite normals)
  return (unsigned short)(u >> 16);
}

// ---------------------------------------------------------------------------
// W -> bf16, once. Wbf lives in d_out (128 KB): attn_t fully overwrites O
// afterwards; stream order (w2bf -> conv -> attn_t) makes the aliasing safe.
// ---------------------------------------------------------------------------
__global__ __launch_bounds__(256) void w2bf(const float* __restrict__ W,
                                            unsigned short* __restrict__ Wbf) {
  const int i = (blockIdx.x * 256 + threadIdx.x) * 4;  // grid 64 -> 65536
  const float4 w4 = *(const float4*)&W[i];
  bf16x4 b;
  b.x = (short)f2bf(w4.x);
  b.y = (short)f2bf(w4.y);
  b.z = (short)f2bf(w4.z);
  b.w = (short)f2bf(w4.w);
  *(bf16x4*)&Wbf[i] = b;
}

// ---------------------------------------------------------------------------
// 1x1 conv v4 (unchanged from R6): W staged once into 130KB LDS, V dbuf.
// ---------------------------------------------------------------------------
__global__ __launch_bounds__(512) void conv1x1_v4(
    const float* __restrict__ V, const unsigned short* __restrict__ Wbf,
    const float* __restrict__ bias, float* __restrict__ PV) {
  __shared__ unsigned short sW[256 * 260];   // 130 KB, row stride 260
  __shared__ unsigned short sV[2][128 * 40]; // [buf][x][c], 2 x 10 KB
  const int tid = threadIdx.x;
  const int x0 = blockIdx.x * 128;  // grid 256
  const int lane = tid & 63;
  const int wv = tid >> 6;   // 0..7
  const int m = lane & 15;   // MFMA free-dim index
  const int q = lane >> 4;   // MFMA quad 0..3

  // ---- stage W once: thread copies o = tid>>1, half = (tid&1)*128 ----
  {
    const int o = tid >> 1;
    const int half = (tid & 1) * 128;
#pragma unroll
    for (int r = 0; r < 16; ++r)
      *(bf16x8*)&sW[o * 260 + half + r * 8] =
          *(const bf16x8*)&Wbf[o * 256 + half + r * 8];
  }

  // ---- V staging map: c_s = tid>>4 (0..31), x8 = (tid&15)*8 ----
  const int c_s = tid >> 4;
  const int x8 = (tid & 15) * 8;
  const float* __restrict__ vstage = V + (size_t)c_s * THW + x0 + x8;

  // stage k-step 0 into sV[0]
  {
    const float4 va = *(const float4*)&vstage[0];
    const float4 vb = *(const float4*)&vstage[4];
    sV[0][(x8 + 0) * 40 + c_s] = f2bf(va.x);
    sV[0][(x8 + 1) * 40 + c_s] = f2bf(va.y);
    sV[0][(x8 + 2) * 40 + c_s] = f2bf(va.z);
    sV[0][(x8 + 3) * 40 + c_s] = f2bf(va.w);
    sV[0][(x8 + 4) * 40 + c_s] = f2bf(vb.x);
    sV[0][(x8 + 5) * 40 + c_s] = f2bf(vb.y);
    sV[0][(x8 + 6) * 40 + c_s] = f2bf(vb.z);
    sV[0][(x8 + 7) * 40 + c_s] = f2bf(vb.w);
  }
  __syncthreads();

  f32x4 acc[2][8];
#pragma unroll
  for (int i = 0; i < 2; ++i)
#pragma unroll
    for (int j = 0; j < 8; ++j)
      acc[i][j] = (f32x4){0.f, 0.f, 0.f, 0.f};

  for (int kk = 0; kk < 8; ++kk) {
    const int cur = kk & 1;
    float4 pva, pvb;
    if (kk < 7) {  // prefetch next V chunk; completes under the MFMAs
      pva = *(const float4*)&vstage[(size_t)(kk + 1) * 32 * THW];
      pvb = *(const float4*)&vstage[(size_t)(kk + 1) * 32 * THW + 4];
    }
    bf16x8 fa[2], fb[8];
#pragma unroll
    for (int i = 0; i < 2; ++i)
      fa[i] = *(const bf16x8*)&sW[(wv * 32 + i * 16 + m) * 260 + kk * 32 + q * 8];
#pragma unroll
    for (int j = 0; j < 8; ++j)
      fb[j] = *(const bf16x8*)&sV[cur][(j * 16 + m) * 40 + q * 8];
#pragma unroll
    for (int i = 0; i < 2; ++i)
#pragma unroll
      for (int j = 0; j < 8; ++j)
        acc[i][j] = __builtin_amdgcn_mfma_f32_16x16x32_bf16(fa[i], fb[j], acc[i][j], 0, 0, 0);
    if (kk < 7) {
      const int nb = cur ^ 1;
      sV[nb][(x8 + 0) * 40 + c_s] = f2bf(pva.x);
      sV[nb][(x8 + 1) * 40 + c_s] = f2bf(pva.y);
      sV[nb][(x8 + 2) * 40 + c_s] = f2bf(pva.z);
      sV[nb][(x8 + 3) * 40 + c_s] = f2bf(pva.w);
      sV[nb][(x8 + 4) * 40 + c_s] = f2bf(pvb.x);
      sV[nb][(x8 + 5) * 40 + c_s] = f2bf(pvb.y);
      sV[nb][(x8 + 6) * 40 + c_s] = f2bf(pvb.z);
      sV[nb][(x8 + 7) * 40 + c_s] = f2bf(pvb.w);
    }
    __syncthreads();
  }

  // ---- epilogue ----
#pragma unroll
  for (int i = 0; i < 2; ++i) {
#pragma unroll
    for (int r = 0; r < 4; ++r) {
      const int o = wv * 32 + i * 16 + q * 4 + r;
      const float bo = bias[o];
#pragma unroll
      for (int j = 0; j < 8; ++j)
        PV[(size_t)o * THW + x0 + j * 16 + m] = acc[i][j][r] + bo;
    }
  }
}

// ---------------------------------------------------------------------------
// t axis v2. R6 version was grid-capped at 2 blocks/CU x 4 waves = 2/SIMD.
// v2: hw-tile 128 -> grid 1024 = 4 blocks/CU = 4 waves/SIMD, 1 c per thread
// (acc[8] f32x4 = 32 VGPR). A-loads broadcast across the two c-halves of a
// wave (same address); pv loads two 512B segments. s ascending -> identical
// accumulation order.
// ---------------------------------------------------------------------------
__global__ __launch_bounds__(256) void attn_t(
    const float* __restrict__ A, const float* __restrict__ PV,
    float* __restrict__ O) {
  const int b = blockIdx.x;  // hd + 8*(cb + 4*xt), grid 1024
  const int hd = b & 7;
  const int cb = (b >> 3) & 3;
  const int xt = b >> 5;  // 0..31
  const int tid = threadIdx.x;
  const int xi = xt * 128 + (tid & 31) * 4;  // hw float offset
  const int c = cb * 8 + (tid >> 5);         // 0..31 within head

  const float* __restrict__ At = A + (size_t)hd * SS * THW + xi;
  const size_t pvh = (size_t)hd * 32 * THW;
  const float* __restrict__ pvc = PV + pvh + (size_t)c * THW + xi;

  f32x4 acc[8];
#pragma unroll
  for (int t = 0; t < 8; ++t) acc[t] = (f32x4){0.f, 0.f, 0.f, 0.f};

  for (int s = 0; s < 8; ++s) {
    const f32x4 pvv = *(const f32x4*)&pvc[(size_t)s * HWP];
#pragma unroll
    for (int t = 0; t < 8; ++t) {
      const f32x4 a = *(const f32x4*)&At[(size_t)s * THW + (size_t)t * HWP];
      acc[t] += a * pvv;
    }
  }

#pragma unroll
  for (int t = 0; t < 8; ++t)
    *(f32x4*)&O[pvh + (size_t)c * THW + (size_t)t * HWP + xi] = acc[t];
}

// ---------------------------------------------------------------------------
// h axis v7, RMW on O. R6 was grid-capped: 256 blocks on 256 CUs = 1 blk/CU
// no matter the LDS (occupancy 19%, the latency-bound disease). v7 splits c
// across blocks (chb, 16 c each): grid 512, slab 32KB -> 2 blk/CU = 16
// waves/CU = 4/SIMD. Per-wave tile: q = qb*16 + wv*2 + qi (qi 0..1),
// c = chb*16 + g*4 + cl -> acc[2][4] f32x4 (32 VGPR), no intra-block A-row
// duplication anymore. Accumulation order unchanged (acc from O, p
// ascending) -> bitwise identical. Plain __launch_bounds__ (min-waves arg
// caused VGPR-64 spill in R3/R4).
// ---------------------------------------------------------------------------
__global__ __launch_bounds__(512) void attn_h(
    const float* __restrict__ A, const float* __restrict__ PV,
    float* __restrict__ O) {
  const int b = blockIdx.x;  // hd + 8*(chb + 2*(qb + 4*tq)), grid 512
  const int hd = b & 7;
  const int chb = (b >> 3) & 1;
  const int qb = (b >> 4) & 3;
  const int tq = b >> 6;  // 0..7
  const int tid = threadIdx.x;
  const int lane = tid & 63;
  const int wv = tid >> 6;         // 0..7
  const int w4 = (lane & 15) * 4;  // w float-offset (f32x4)
  const int cl = lane >> 4;        // 0..3
  const int q0 = qb * 16 + wv * 2;
  const int c0 = chb * 16;

  __shared__ float slab[2][4 * 16 * 64];  // [buf][pp][c][w] = 32 KB

  const float* __restrict__ Ab = A + (size_t)hd * SS * THW + (size_t)tq * HWP;
  const size_t pvh = (size_t)hd * 32 * THW;
  const float* __restrict__ PVh = PV + pvh;

  // init acc from O (t-part, RMW); issued first so latency hides under staging
  f32x4 acc[2][4];  // [qi][g]
#pragma unroll
  for (int qi = 0; qi < 2; ++qi) {
    const int q = q0 + qi;
#pragma unroll
    for (int g = 0; g < 4; ++g) {
      const int c = c0 + g * 4 + cl;
      acc[qi][g] =
          *(const f32x4*)&O[pvh + (size_t)c * THW + (size_t)tq * HWP + q * 64 + w4];
    }
  }

  // staging map: thread covers pp = pp0 + 2r (r 0..1) at fixed (c_s, w4s)
  const int w4s = (tid & 15) * 4;
  const int c_s = (tid >> 4) & 15;   // 0..15
  const int pp0 = tid >> 8;          // 0..1
  const float* __restrict__ pvstage =
      PVh + (size_t)(c0 + c_s) * THW + (size_t)tq * HWP + w4s;
  const int sbase = c_s * 64 + w4s;  // float offset within a pp plane (16c*64w)

  // chunk-0 prefetch (p = 0..3)
  f32x4 stg[2];
#pragma unroll
  for (int r = 0; r < 2; ++r)
    stg[r] = *(const f32x4*)&pvstage[(pp0 + 2 * r) * 64];
#pragma unroll
  for (int r = 0; r < 2; ++r)
    *(f32x4*)&slab[0][(pp0 + 2 * r) * 1024 + sbase] = stg[r];
  __syncthreads();

  // ---- h axis: 16 chunks of 4 p, double-buffered, 1 sync/chunk ----
  for (int ck = 0; ck < 16; ++ck) {
    const int cur = ck & 1;
    if (ck < 15) {
      // issue next chunk's global loads now; they complete under the FMAs
#pragma unroll
      for (int r = 0; r < 2; ++r)
        stg[r] = *(const f32x4*)&pvstage[((ck + 1) * 4 + pp0 + 2 * r) * 64];
    }
#pragma unroll
    for (int pp = 0; pp < 4; ++pp) {
      const int p = ck * 4 + pp;
      f32x4 a[2];
#pragma unroll
      for (int qi = 0; qi < 2; ++qi) {
        const int q = q0 + qi;
        const int row = p - (q < p ? 1 : 0);  // 0..63 (p==q load masked)
        f32x4 av = *(const f32x4*)&Ab[(size_t)(8 + row) * THW + q * 64 + w4];
        if (q == p) av = (f32x4){0.f, 0.f, 0.f, 0.f};
        a[qi] = av;
      }
      f32x4 v[4];
#pragma unroll
      for (int g = 0; g < 4; ++g)
        v[g] = *(const f32x4*)&slab[cur][pp * 1024 + (g * 4 + cl) * 64 + w4];
#pragma unroll
      for (int qi = 0; qi < 2; ++qi)
#pragma unroll
        for (int g = 0; g < 4; ++g)
          acc[qi][g] += a[qi] * v[g];
    }
    if (ck < 15) {
#pragma unroll
      for (int r = 0; r < 2; ++r)
        *(f32x4*)&slab[cur ^ 1][(pp0 + 2 * r) * 1024 + sbase] = stg[r];
    }
    __syncthreads();
  }

  // ---- store (t + h partial) ----
#pragma unroll
  for (int qi = 0; qi < 2; ++qi) {
    const int q = q0 + qi;
#pragma unroll
    for (int g = 0; g < 4; ++g) {
      const int c = c0 + g * 4 + cl;
      *(f32x4*)&O[pvh + (size_t)c * THW + (size_t)tq * HWP + q * 64 + w4] =
          acc[qi][g];
    }
  }
}

// ---------------------------------------------------------------------------
// w axis, read-modify-write on O. (unchanged; 4 blocks/CU already)
// ---------------------------------------------------------------------------
__global__ __launch_bounds__(256) void attn_w(
    const float* __restrict__ A, const float* __restrict__ PV,
    float* __restrict__ O) {
  const int b = blockIdx.x;  // hb + 16*tq + 128*hd, grid 1024
  const int hb = b & 15;
  const int tq = (b >> 4) & 7;
  const int hd = b >> 7;
  const int tid = threadIdx.x;
  const int wq = tid & 63;
  const int cg = tid >> 6;  // 0..3
  const int h0 = hb * 4;

  __shared__ float slab[32 * 64 * 4];  // [c][pw][h4]

  const float* __restrict__ Ab = A + (size_t)hd * SS * THW + (size_t)tq * HWP;
  const size_t pvh = (size_t)hd * 32 * THW;

  // stage pv w-slab (transpose w<->h minor dims)
#pragma unroll 4
  for (int i = 0; i < 8; ++i) {
    const int fid = tid + i * 256;     // 0..2047
    const int w4s = (fid & 15) * 4;    // 0..60
    const int h = (fid >> 4) & 3;      // 0..3
    const int c = fid >> 6;            // 0..31
    const f32x4 v =
        *(const f32x4*)&PV[pvh + (size_t)c * THW + (size_t)tq * HWP + (h0 + h) * 64 + w4s];
    slab[(c * 64 + w4s + 0) * 4 + h] = v.x;
    slab[(c * 64 + w4s + 1) * 4 + h] = v.y;
    slab[(c * 64 + w4s + 2) * 4 + h] = v.z;
    slab[(c * 64 + w4s + 3) * 4 + h] = v.w;
  }

  // prefetch current O tile (RMW) while staging completes
  f32x4 racc[8];
#pragma unroll
  for (int ci = 0; ci < 8; ++ci) {
    const int c = cg + ci * 4;
    f32x4 r;
#pragma unroll
    for (int hh = 0; hh < 4; ++hh)
      r[hh] = O[pvh + (size_t)c * THW + (size_t)tq * HWP + (h0 + hh) * 64 + wq];
    racc[ci] = r;
  }
  __syncthreads();

#pragma unroll 4
  for (int p = 0; p < 64; ++p) {
    const int row = 71 + p - (wq <= p ? 1 : 0);  // 70..133, in-bounds always
    const float* pa = Ab + (size_t)row * THW + h0 * 64 + wq;
    f32x4 a;
    a.x = pa[0];
    a.y = pa[64];
    a.z = pa[128];
    a.w = pa[192];
    if (p == wq) a = (f32x4){0.f, 0.f, 0.f, 0.f};
#pragma unroll
    for (int ci = 0; ci < 8; ++ci) {
      const f32x4 v = *(const f32x4*)&slab[(cg + ci * 4) * 256 + p * 4];
      racc[ci] += a * v;
    }
  }

  // ---- store (RMW result) ----
#pragma unroll
  for (int ci = 0; ci < 8; ++ci) {
    const int c = cg + ci * 4;
#pragma unroll
    for (int hh = 0; hh < 4; ++hh)
      O[pvh + (size_t)c * THW + (size_t)tq * HWP + (h0 + hh) * 64 + wq] = racc[ci][hh];
  }
}

extern "C" void kernel_launch(void* const* d_in, const int* in_sizes, int n_in,
                              void* d_out, int out_size, void* d_ws, size_t ws_size,
                              hipStream_t stream) {
  const float* A = (const float*)d_in[0];     // [8*134][8][64][64]
  const float* V = (const float*)d_in[1];     // [256][8][64][64]
  const float* W = (const float*)d_in[2];     // [256][256] (o, c)
  const float* bias = (const float*)d_in[3];  // [256]
  float* out = (float*)d_out;                 // [256][8][64][64]
  float* pv = (float*)d_ws;                   // 32 MB scratch: pv[o][t][h][w]

  unsigned short* Wbf = (unsigned short*)d_out;  // temp 128 KB, dead after conv

  w2bf<<<dim3(64), 256, 0, stream>>>(W, Wbf);
  conv1x1_v4<<<dim3(256), 512, 0, stream>>>(V, Wbf, bias, pv);
  attn_t<<<dim3(1024), 256, 0, stream>>>(A, pv, out);
  attn_h<<<dim3(512), 512, 0, stream>>>(A, pv, out);
  attn_w<<<dim3(1024), 256, 0, stream>>>(A, pv, out);
}